// Round 5
// baseline (71.190 us; speedup 1.0000x reference)
//
#include <hip/hip_runtime.h>

// AffineExponential: y = expm(t*W) @ x + bias*t,  ljd = diag(W)*t
// Taylor action batched as GEMMs: V_0 = X; V_k = (W V_{k-1}) * diag(t/k);
// y = sum_k V_k. K=10 (||tW|| <= ~2.2 -> tail ~2e-4, << bf16-v noise 0.031).
//
// Round-4: round 3 (MFMA, 256 blocks) left ~18us inferred kernel time —
// latency-bound at 1 block/CU / 1 wave/SIMD: nothing hides the per-k
// barrier + LDS round trip + 8-deep MFMA chains + uncoalesced W-load
// startup. Fix: SPB 16->8 (cols 8-15 dummy zeros; MFMA pipe is ~free),
// grid 512 -> 2 blocks/CU so co-resident block hides stalls; MFMA chain
// depth 8->4 (split accumulators); KT 12->10.
// Precision: W = hi+lo bf16 split (2 MFMAs/K-step); v bf16 per step.

#define DD  128
#define KT  10
#define SPB 8       // real samples per block (MFMA cols 8-15 are zero dummies)
#define KS  136     // vs row stride in bf16 elems: 272B, 16B-aligned, bank-spread

typedef short s16x8 __attribute__((ext_vector_type(8)));   // 8 bf16 (4 VGPRs)
typedef short s16x4 __attribute__((ext_vector_type(4)));
typedef float f32x4 __attribute__((ext_vector_type(4)));

__device__ inline unsigned short f2bf(float f) {           // fp32 -> bf16 (RNE)
    unsigned int u = __float_as_uint(f);
    u += 0x7FFFu + ((u >> 16) & 1u);
    return (unsigned short)(u >> 16);
}
__device__ inline float bf2f(unsigned short h) {
    return __uint_as_float(((unsigned int)h) << 16);
}

__global__ __launch_bounds__(256, 2)
void affine_exp_kernel(const float* __restrict__ x,
                       const float* __restrict__ t,
                       const float* __restrict__ weight,
                       const float* __restrict__ bias,
                       float* __restrict__ out, int B)
{
    __shared__ unsigned short vs[2][16 * KS];   // vs[b][n*KS + k], bf16

    const int tid = threadIdx.x;
    const int w   = tid >> 6;        // wave 0..3 -> rows [32w, 32w+32)
    const int l   = tid & 63;
    const int n   = l & 15;          // MFMA column (sample for n<8, dummy else)
    const int q   = l >> 4;          // quad
    const int s0  = blockIdx.x * SPB;
    const int nn  = n & 7;           // clamped sample index (safe loads)

    const float tn = t[s0 + nn];

    // ---- W A-fragments (hi/lo bf16 split), from global, once ----
    // A[m = lane&15][k = quad*8 + j]; tile r: rows 32w+16r+[0,16); kstep s: 32s+[0,32)
    s16x8 wahi[2][4], walo[2][4];
#pragma unroll
    for (int r = 0; r < 2; ++r) {
        const int m = w * 32 + r * 16 + n;
#pragma unroll
        for (int s = 0; s < 4; ++s) {
            const float* wp = weight + (size_t)m * DD + s * 32 + q * 8;
            const f32x4 f0 = *reinterpret_cast<const f32x4*>(wp);
            const f32x4 f1 = *reinterpret_cast<const f32x4*>(wp + 4);
            s16x8 h, lo;
#pragma unroll
            for (int j = 0; j < 4; ++j) {
                const unsigned short hb0 = f2bf(f0[j]);
                const unsigned short hb1 = f2bf(f1[j]);
                h[j]      = (short)hb0;
                h[j + 4]  = (short)hb1;
                lo[j]     = (short)f2bf(f0[j] - bf2f(hb0));
                lo[j + 4] = (short)f2bf(f1[j] - bf2f(hb1));
            }
            wahi[r][s] = h;
            walo[r][s] = lo;
        }
    }

    // ---- y init = v_0 = x in MFMA C-layout (col=n, row=q*4+reg) ----
    const int g0 = w * 32 + q * 4;
    f32x4 y0 = *reinterpret_cast<const f32x4*>(x + (size_t)(s0 + nn) * DD + g0);
    f32x4 y1 = *reinterpret_cast<const f32x4*>(x + (size_t)(s0 + nn) * DD + g0 + 16);

    // ---- stage v_0 = bf16(x) transposed into vs[0]; zero dummy cols ----
#pragma unroll
    for (int i = 0; i < 4; ++i) {
        const int d = q * 32 + i * 8;
        s16x8 p = {0, 0, 0, 0, 0, 0, 0, 0};
        if (n < SPB) {
            const f32x4 a = *reinterpret_cast<const f32x4*>(x + (size_t)(s0 + n) * DD + d);
            const f32x4 b = *reinterpret_cast<const f32x4*>(x + (size_t)(s0 + n) * DD + d + 4);
#pragma unroll
            for (int j = 0; j < 4; ++j) {
                p[j]     = (short)f2bf(a[j]);
                p[j + 4] = (short)f2bf(b[j]);
            }
        }
        *reinterpret_cast<s16x8*>(&vs[0][n * KS + d]) = p;
    }
    __syncthreads();

    // ---- Taylor loop: 1 barrier per k, ping-pong, split MFMA chains ----
    int cur = 0;
#pragma unroll
    for (int k = 1; k <= KT; ++k) {
        const unsigned short* vp = &vs[cur][n * KS + q * 8];
        const s16x8 vb0 = *reinterpret_cast<const s16x8*>(vp);
        const s16x8 vb1 = *reinterpret_cast<const s16x8*>(vp + 32);
        const s16x8 vb2 = *reinterpret_cast<const s16x8*>(vp + 64);
        const s16x8 vb3 = *reinterpret_cast<const s16x8*>(vp + 96);

        f32x4 a0a = {0.f, 0.f, 0.f, 0.f}, a0b = {0.f, 0.f, 0.f, 0.f};
        f32x4 a1a = {0.f, 0.f, 0.f, 0.f}, a1b = {0.f, 0.f, 0.f, 0.f};
        // chain depth 4 per accumulator; 4 independent chains interleave
        a0a = __builtin_amdgcn_mfma_f32_16x16x32_bf16(wahi[0][0], vb0, a0a, 0, 0, 0);
        a1a = __builtin_amdgcn_mfma_f32_16x16x32_bf16(wahi[1][0], vb0, a1a, 0, 0, 0);
        a0b = __builtin_amdgcn_mfma_f32_16x16x32_bf16(wahi[0][2], vb2, a0b, 0, 0, 0);
        a1b = __builtin_amdgcn_mfma_f32_16x16x32_bf16(wahi[1][2], vb2, a1b, 0, 0, 0);
        a0a = __builtin_amdgcn_mfma_f32_16x16x32_bf16(walo[0][0], vb0, a0a, 0, 0, 0);
        a1a = __builtin_amdgcn_mfma_f32_16x16x32_bf16(walo[1][0], vb0, a1a, 0, 0, 0);
        a0b = __builtin_amdgcn_mfma_f32_16x16x32_bf16(walo[0][2], vb2, a0b, 0, 0, 0);
        a1b = __builtin_amdgcn_mfma_f32_16x16x32_bf16(walo[1][2], vb2, a1b, 0, 0, 0);
        a0a = __builtin_amdgcn_mfma_f32_16x16x32_bf16(wahi[0][1], vb1, a0a, 0, 0, 0);
        a1a = __builtin_amdgcn_mfma_f32_16x16x32_bf16(wahi[1][1], vb1, a1a, 0, 0, 0);
        a0b = __builtin_amdgcn_mfma_f32_16x16x32_bf16(wahi[0][3], vb3, a0b, 0, 0, 0);
        a1b = __builtin_amdgcn_mfma_f32_16x16x32_bf16(wahi[1][3], vb3, a1b, 0, 0, 0);
        a0a = __builtin_amdgcn_mfma_f32_16x16x32_bf16(walo[0][1], vb1, a0a, 0, 0, 0);
        a1a = __builtin_amdgcn_mfma_f32_16x16x32_bf16(walo[1][1], vb1, a1a, 0, 0, 0);
        a0b = __builtin_amdgcn_mfma_f32_16x16x32_bf16(walo[0][3], vb3, a0b, 0, 0, 0);
        a1b = __builtin_amdgcn_mfma_f32_16x16x32_bf16(walo[1][3], vb3, a1b, 0, 0, 0);

        const float c = tn * (1.0f / (float)k);
        f32x4 a0 = (a0a + a0b) * c;
        f32x4 a1 = (a1a + a1b) * c;
        y0 += a0;
        y1 += a1;

        s16x4 p0, p1;
#pragma unroll
        for (int j = 0; j < 4; ++j) {
            p0[j] = (short)f2bf(a0[j]);
            p1[j] = (short)f2bf(a1[j]);
        }
        unsigned short* wq = &vs[cur ^ 1][n * KS + g0];
        *reinterpret_cast<s16x4*>(wq)      = p0;
        *reinterpret_cast<s16x4*>(wq + 16) = p1;
        __syncthreads();
        cur ^= 1;
    }

    // ---- epilogue: y += bias*t, store (real samples only) ----
    if (n < SPB) {
        const f32x4 b0 = *reinterpret_cast<const f32x4*>(bias + g0);
        const f32x4 b1 = *reinterpret_cast<const f32x4*>(bias + g0 + 16);
        const f32x4 o0 = y0 + b0 * tn;
        const f32x4 o1 = y1 + b1 * tn;
        *reinterpret_cast<f32x4*>(out + (size_t)(s0 + n) * DD + g0)      = o0;
        *reinterpret_cast<f32x4*>(out + (size_t)(s0 + n) * DD + g0 + 16) = o1;
    }

    // ---- ljd = diag(W) * t  (coalesced f32x4 stores) ----
    {
        const int ns = tid >> 5;            // sample 0..7
        const int dg = (tid & 31) << 2;     // dim group, consecutive across lanes
        const float ts = t[s0 + ns];
        f32x4 o;
#pragma unroll
        for (int j = 0; j < 4; ++j)
            o[j] = weight[(size_t)(dg + j) * DD + dg + j] * ts;
        *reinterpret_cast<f32x4*>(out + (size_t)B * DD + (size_t)(s0 + ns) * DD + dg) = o;
    }
}

extern "C" void kernel_launch(void* const* d_in, const int* in_sizes, int n_in,
                              void* d_out, int out_size, void* d_ws, size_t ws_size,
                              hipStream_t stream) {
    const float* x      = (const float*)d_in[0];
    const float* t      = (const float*)d_in[1];
    const float* weight = (const float*)d_in[2];
    const float* bias   = (const float*)d_in[3];
    float* out = (float*)d_out;

    const int B = in_sizes[1];          // one scalar t per sample
    const int blocks = B / SPB;         // 4096/8 = 512 -> 2 blocks/CU

    affine_exp_kernel<<<blocks, 256, 0, stream>>>(x, t, weight, bias, out, B);
}